// Round 4
// baseline (544.241 us; speedup 1.0000x reference)
//
#include <hip/hip_runtime.h>
#include <hip/hip_bf16.h>

typedef unsigned short ushort_t;
typedef __attribute__((ext_vector_type(8))) short bf16x8;   // 8 bf16 = 4 VGPRs
typedef __attribute__((ext_vector_type(4))) float f32x4;    // 4 fp32 acc

#define MDIM 2048
#define NDIM 4096

__device__ __forceinline__ ushort_t to_bf16(float f) {
    __hip_bfloat16 h = __float2bfloat16(f);
    return *reinterpret_cast<ushort_t*>(&h);
}

// ---------------- prep: fp32 -> bf16 cast ----------------
__global__ void cast_bf16_kernel(const float* __restrict__ in, ushort_t* __restrict__ out, int n) {
    int i = blockIdx.x * blockDim.x + threadIdx.x;
    if (i < n) out[i] = to_bf16(in[i]);
}

// ---------------- prep: W[K][N] fp32 -> WT[N][K] bf16 ----------------
__global__ void transpose_cast_kernel(const float* __restrict__ W, ushort_t* __restrict__ WT,
                                      int K, int N) {
    __shared__ float tile[32][33];
    const int tx = threadIdx.x, ty = threadIdx.y;  // (32, 8)
    const int n0 = blockIdx.x * 32, k0 = blockIdx.y * 32;
#pragma unroll
    for (int r = 0; r < 4; ++r)
        tile[ty + r * 8][tx] = W[(size_t)(k0 + ty + r * 8) * N + n0 + tx];
    __syncthreads();
    const int t = ty * 32 + tx;
    const int nl = t >> 3;          // 0..31 : local n
    const int kc = (t & 7) * 4;     // 0..28 : k chunk of 4
    ushort4 o;
    o.x = to_bf16(tile[kc + 0][nl]);
    o.y = to_bf16(tile[kc + 1][nl]);
    o.z = to_bf16(tile[kc + 2][nl]);
    o.w = to_bf16(tile[kc + 3][nl]);
    *reinterpret_cast<ushort4*>(&WT[(size_t)(n0 + nl) * K + k0 + kc]) = o;
}

// ---------------- GEMM v5: B direct from global (flatmm style), A via LDS ----------------
// C[M][N] = act(A[M][K] @ BT[N][K]^T + bias)
// BM=128, BN=256, BK=64, 8 waves (2Mx4N), wave tile 64x64 (4x4 frags of 16x16x32).
// Grid (N/256, M/128) = 16x16 = 256 blocks = 1 block/CU.
// v4 post-mortem: tile time 2775cyc == LDS-serve(1536) + MFMA(1240) EXACTLY ->
// zero overlap; the barrier-aligned waves saturate the LDS port (128 b128
// reads/tile), then MFMA. Port demand is the floor, so v5 removes B from LDS:
// B-fragments load straight from global into VGPRs (bytes identical to what
// LDB_ produced -> numerics bitwise unchanged). B is L2-resident: grid x%8
// pins each n0-slice pair (2x2MB) to one XCD's 4MB L2. B-frags of tile tt+1
// prefetch during tile tt. LDS holds A only (3 x 16KB buffers, global_load_lds,
// chunk-XOR swizzle, 64 reads/tile). Pipes per tile: MFMA 1240 | VMEM-B ~1170
// | LDS 768 -> they overlap (different pipes) instead of serializing.
// vmcnt bookkeeping (issue order pinned by sched_barrier(0)):
//   per tile: [8 b-loads(tt+1)] < [2 GLD_A(tt+2)] ; end-of-tile vmcnt(2)
//   drains b(tt+1) + GLD_A(tt+1) (older), keeps GLD_A(tt+2) in flight.

#define GLD(gp, lp) __builtin_amdgcn_global_load_lds(                      \
        (const __attribute__((address_space(1))) void*)(gp),               \
        (__attribute__((address_space(3))) void*)(lp), 16, 0, 0)

#define MFMA(d, a, b) d = __builtin_amdgcn_mfma_f32_16x16x32_bf16(a, b, d, 0, 0, 0)

template <typename OutT, bool RELU>
__global__ __launch_bounds__(512, 2) void gemm_p8(const ushort_t* __restrict__ A,
                                                  const ushort_t* __restrict__ BT,
                                                  const float* __restrict__ bias,
                                                  OutT* __restrict__ C, int Kdim) {
    __shared__ __align__(16) ushort_t As[3][128 * 64];   // 48 KB total

    const int t = threadIdx.x;
    const int l = t & 63;
    const int w = t >> 6;          // wave 0..7
    const int l16 = l & 15;
    const int quad = l >> 4;
    const int wr = w >> 2;         // 0..1  (M)
    const int wc = w & 3;          // 0..3  (N)
    const int m0 = blockIdx.y * 128;
    const int n0 = blockIdx.x * 256;

    f32x4 acc[4][4];
#pragma unroll
    for (int i = 0; i < 4; ++i)
#pragma unroll
        for (int j = 0; j < 4; ++j) acc[i][j] = (f32x4){0.f, 0.f, 0.f, 0.f};

    // --- A staging addressing (unchanged, verified conflict-free) ---
    const int srow = w * 8 + (l >> 3);
    const int scol = ((l & 7) ^ (l >> 3)) * 8;   // swizzled 16B chunk within the K-tile
    const ushort_t* gA0 = A + (size_t)(m0 + srow) * Kdim + scol;
    const ushort_t* gA1 = A + (size_t)(m0 + 64 + srow) * Kdim + scol;
    const int ldsW = w * 8 * 64;   // wave-uniform element offset of this wave's 8 rows

    // A fragment reads: row = wr*64 + i*16 + l16, chunk slot = (kk*4+quad)^(row&7)
    const int swz = l16 & 7;
#define LDA_(base, i, kk) (*(const bf16x8*)&(base)[(wr * 64 + (i) * 16 + l16) * 64 + ((((kk) * 4 + quad) ^ swz) * 8)])

    // B fragment loads, direct from global. Bytes == old LDB_ output:
    // BT[(n0 + wc*64 + j*16 + l16)*K + tt*64 + (kk*4+quad)*8 .. +8)
    const ushort_t* pB0 = BT + (size_t)(n0 + wc * 64 + 0 * 16 + l16) * Kdim + quad * 8;
    const ushort_t* pB1 = BT + (size_t)(n0 + wc * 64 + 1 * 16 + l16) * Kdim + quad * 8;
    const ushort_t* pB2 = BT + (size_t)(n0 + wc * 64 + 2 * 16 + l16) * Kdim + quad * 8;
    const ushort_t* pB3 = BT + (size_t)(n0 + wc * 64 + 3 * 16 + l16) * Kdim + quad * 8;
#define BL(p, kk, ttn) (*reinterpret_cast<const bf16x8*>((p) + (size_t)(ttn) * 64 + (kk) * 32))

#define STAGE_A(buf, koff) do {                         \
        GLD(gA0 + (koff), &As[buf][ldsW]);              \
        GLD(gA1 + (koff), &As[buf][ldsW + 64 * 64]);    \
    } while (0)

    // 16 MFMAs at one kk (i-major, j-minor -> per-acc order identical to prior versions)
#define MFMA16(a0, a1, a2, a3, b0, b1, b2, b3)                     \
        MFMA(acc[0][0], a0, b0); MFMA(acc[0][1], a0, b1);          \
        MFMA(acc[0][2], a0, b2); MFMA(acc[0][3], a0, b3);          \
        MFMA(acc[1][0], a1, b0); MFMA(acc[1][1], a1, b1);          \
        MFMA(acc[1][2], a1, b2); MFMA(acc[1][3], a1, b3);          \
        MFMA(acc[2][0], a2, b0); MFMA(acc[2][1], a2, b1);          \
        MFMA(acc[2][2], a2, b2); MFMA(acc[2][3], a2, b3);          \
        MFMA(acc[3][0], a3, b0); MFMA(acc[3][1], a3, b1);          \
        MFMA(acc[3][2], a3, b2); MFMA(acc[3][3], a3, b3)

    const int nt = Kdim >> 6;      // K-tiles of 64 (nt >= 4 for K in {256, 4096})

    // ---- prologue: GLD_A(0) < b(0) < GLD_A(1); vmcnt(2) keeps GLD_A(1) ----
    STAGE_A(0, 0);
    __builtin_amdgcn_sched_barrier(0);
    bf16x8 bc00 = BL(pB0, 0, 0), bc01 = BL(pB0, 1, 0);
    bf16x8 bc10 = BL(pB1, 0, 0), bc11 = BL(pB1, 1, 0);
    bf16x8 bc20 = BL(pB2, 0, 0), bc21 = BL(pB2, 1, 0);
    bf16x8 bc30 = BL(pB3, 0, 0), bc31 = BL(pB3, 1, 0);
    __builtin_amdgcn_sched_barrier(0);
    STAGE_A(1, 64);
    asm volatile("s_waitcnt vmcnt(2)" ::: "memory");
    __builtin_amdgcn_s_barrier();

    for (int tt = 0; tt < nt; ++tt) {
        const int buf = tt % 3;
        const int nb = (tt + 2) % 3;
        const bool more = (tt + 2) < nt;

        const ushort_t* __restrict__ Ab = &As[buf][0];

        // A fragments of this K-tile from LDS (compiler uses counted lgkmcnt)
        bf16x8 a00 = LDA_(Ab, 0, 0), a01 = LDA_(Ab, 1, 0), a02 = LDA_(Ab, 2, 0), a03 = LDA_(Ab, 3, 0);
        bf16x8 a10 = LDA_(Ab, 0, 1), a11 = LDA_(Ab, 1, 1), a12 = LDA_(Ab, 2, 1), a13 = LDA_(Ab, 3, 1);

        // B fragments of tile tt+1 prefetch (must issue BEFORE the GLDs)
        bf16x8 bn00, bn01, bn10, bn11, bn20, bn21, bn30, bn31;
        if (tt + 1 < nt) {
            bn00 = BL(pB0, 0, tt + 1); bn01 = BL(pB0, 1, tt + 1);
            bn10 = BL(pB1, 0, tt + 1); bn11 = BL(pB1, 1, tt + 1);
            bn20 = BL(pB2, 0, tt + 1); bn21 = BL(pB2, 1, tt + 1);
            bn30 = BL(pB3, 0, tt + 1); bn31 = BL(pB3, 1, tt + 1);
        }
        __builtin_amdgcn_sched_barrier(0);
        if (more) STAGE_A(nb, (tt + 2) << 6);

        // 32 MFMAs, single barrier-free region, B operands already in VGPRs
        MFMA16(a00, a01, a02, a03, bc00, bc10, bc20, bc30);
        MFMA16(a10, a11, a12, a13, bc01, bc11, bc21, bc31);

        if (tt + 1 < nt) {
            // drain b(tt+1) + GLD_A(tt+1) (older); keep GLD_A(tt+2) if issued
            if (more) asm volatile("s_waitcnt vmcnt(2)" ::: "memory");
            else      asm volatile("s_waitcnt vmcnt(0)" ::: "memory");
            __builtin_amdgcn_s_barrier();
            bc00 = bn00; bc01 = bn01; bc10 = bn10; bc11 = bn11;
            bc20 = bn20; bc21 = bn21; bc30 = bn30; bc31 = bn31;
        }
    }

    // epilogue: C/D layout col=lane&15, row=quad*4+reg (unchanged mapping)
#pragma unroll
    for (int i = 0; i < 4; ++i) {
#pragma unroll
        for (int r = 0; r < 4; ++r) {
            const int grow = m0 + wr * 64 + i * 16 + quad * 4 + r;
#pragma unroll
            for (int j = 0; j < 4; ++j) {
                const int gcol = n0 + wc * 64 + j * 16 + l16;
                float v = acc[i][j][r] + bias[gcol];
                if (RELU) v = fmaxf(v, 0.0f);
                if constexpr (sizeof(OutT) == 2) {
                    C[(size_t)grow * NDIM + gcol] = to_bf16(v);
                } else {
                    C[(size_t)grow * NDIM + gcol] = v;
                }
            }
        }
    }
}

// ---------------- Sinkhorn, factored: P = diag(a) K diag(b) ----------------
// (unchanged — register-resident K, readlane broadcast)
__device__ __forceinline__ float rdl(float v, int l) {
    return __uint_as_float(__builtin_amdgcn_readlane(__float_as_uint(v), l));
}

__global__ __launch_bounds__(64) void sinkhorn_kernel(float* __restrict__ PM) {
    __shared__ __align__(16) float T[64 * 65];  // one-time transpose staging
    const int l = threadIdx.x;
    float* base = PM + (size_t)blockIdx.x * 4096;

    float Kcol[64];  // Kcol[r] = K[r][l]  (column l)
    float Krow[64];  // Krow[c] = K[l][c]  (row l)
#pragma unroll
    for (int r = 0; r < 64; ++r)
        Kcol[r] = __expf(-base[r * 64 + l]);
#pragma unroll
    for (int r = 0; r < 64; ++r)
        T[r * 65 + l] = Kcol[r];
    __syncthreads();
#pragma unroll
    for (int c = 0; c < 64; ++c)
        Krow[c] = T[l * 65 + c];

    float a = 0.0f, b = 1.0f;
    for (int it = 0; it < 1000; ++it) {
        float t1 = 0.0f;  // (K b)_row=l
#pragma unroll
        for (int c = 0; c < 64; ++c)
            t1 = fmaf(Krow[c], rdl(b, c), t1);
        a = 0.015625f / t1;  // r = 1/64

        float t2 = 0.0f;  // (K^T a)_col=l
#pragma unroll
        for (int r = 0; r < 64; ++r)
            t2 = fmaf(Kcol[r], rdl(a, r), t2);
        const float err = fabsf(b * t2 - 0.015625f);
        if (__ballot(err > 1e-6f) == 0ull) break;
        b = 0.015625f / t2;
    }

#pragma unroll
    for (int r = 0; r < 64; ++r)
        base[r * 64 + l] = rdl(a, r) * Kcol[r] * b;
}

extern "C" void kernel_launch(void* const* d_in, const int* in_sizes, int n_in,
                              void* d_out, int out_size, void* d_ws, size_t ws_size,
                              hipStream_t stream) {
    const float* z  = (const float*)d_in[0];
    const float* W1 = (const float*)d_in[1];
    const float* b1 = (const float*)d_in[2];
    const float* W2 = (const float*)d_in[3];
    const float* b2 = (const float*)d_in[4];
    const float* W3 = (const float*)d_in[5];
    const float* b3 = (const float*)d_in[6];
    float* out = (float*)d_out;
    char* ws = (char*)d_ws;

    // workspace layout (bytes)
    ushort_t* W2T = (ushort_t*)(ws + 0);                       // 4096*4096*2 = 32 MB
    ushort_t* W3T = (ushort_t*)(ws + (size_t)33554432);        // 32 MB
    ushort_t* C1b = (ushort_t*)(ws + (size_t)67108864);        // 2048*4096*2 = 16 MB
    ushort_t* C2b = (ushort_t*)(ws + (size_t)83886080);        // 16 MB
    ushort_t* Zb  = (ushort_t*)(ws + (size_t)100663296);       // 2048*256*2 = 1 MB
    ushort_t* W1T = (ushort_t*)(ws + (size_t)101711872);       // 4096*256*2 = 2 MB

    // prep
    cast_bf16_kernel<<<2048, 256, 0, stream>>>(z, Zb, MDIM * 256);
    transpose_cast_kernel<<<dim3(128, 8), dim3(32, 8), 0, stream>>>(W1, W1T, 256, 4096);
    transpose_cast_kernel<<<dim3(128, 128), dim3(32, 8), 0, stream>>>(W2, W2T, 4096, 4096);
    transpose_cast_kernel<<<dim3(128, 128), dim3(32, 8), 0, stream>>>(W3, W3T, 4096, 4096);

    // 3-layer MLP (bf16 MFMA, fp32 accum); layer 3 writes fp32 cost matrix into d_out
    gemm_p8<ushort_t, true><<<dim3(NDIM / 256, MDIM / 128), 512, 0, stream>>>(Zb, W1T, b1, C1b, 256);
    gemm_p8<ushort_t, true><<<dim3(NDIM / 256, MDIM / 128), 512, 0, stream>>>(C1b, W2T, b2, C2b, 4096);
    gemm_p8<float, false><<<dim3(NDIM / 256, MDIM / 128), 512, 0, stream>>>(C2b, W3T, b3, out, 4096);

    // Sinkhorn in-place on d_out (one wave per matrix, register-resident K)
    sinkhorn_kernel<<<2048, 64, 0, stream>>>(out);
}

// Round 5
// 349.826 us; speedup vs baseline: 1.5557x; 1.5557x over previous
//
#include <hip/hip_runtime.h>
#include <hip/hip_bf16.h>

typedef unsigned short ushort_t;
typedef __attribute__((ext_vector_type(8))) short bf16x8;   // 8 bf16 = 4 VGPRs
typedef __attribute__((ext_vector_type(4))) float f32x4;    // 4 fp32 acc

#define MDIM 2048
#define NDIM 4096

__device__ __forceinline__ ushort_t to_bf16(float f) {
    __hip_bfloat16 h = __float2bfloat16(f);
    return *reinterpret_cast<ushort_t*>(&h);
}

// ---------------- prep: fp32 -> bf16 cast ----------------
__global__ void cast_bf16_kernel(const float* __restrict__ in, ushort_t* __restrict__ out, int n) {
    int i = blockIdx.x * blockDim.x + threadIdx.x;
    if (i < n) out[i] = to_bf16(in[i]);
}

// ---------------- prep: W[K][N] fp32 -> WT[N][K] bf16 ----------------
__global__ void transpose_cast_kernel(const float* __restrict__ W, ushort_t* __restrict__ WT,
                                      int K, int N) {
    __shared__ float tile[32][33];
    const int tx = threadIdx.x, ty = threadIdx.y;  // (32, 8)
    const int n0 = blockIdx.x * 32, k0 = blockIdx.y * 32;
#pragma unroll
    for (int r = 0; r < 4; ++r)
        tile[ty + r * 8][tx] = W[(size_t)(k0 + ty + r * 8) * N + n0 + tx];
    __syncthreads();
    const int t = ty * 32 + tx;
    const int nl = t >> 3;          // 0..31 : local n
    const int kc = (t & 7) * 4;     // 0..28 : k chunk of 4
    ushort4 o;
    o.x = to_bf16(tile[kc + 0][nl]);
    o.y = to_bf16(tile[kc + 1][nl]);
    o.z = to_bf16(tile[kc + 2][nl]);
    o.w = to_bf16(tile[kc + 3][nl]);
    *reinterpret_cast<ushort4*>(&WT[(size_t)(n0 + nl) * K + k0 + kc]) = o;
}

// ---------------- GEMM v6: 128x128, 4 waves, 2 blocks/CU ----------------
// C[M][N] = act(A[M][K] @ BT[N][K]^T + bias)
// v5 post-mortem: B-direct-from-global = latency-bound disaster (174us,
// MfmaUtil 15%) - 16-segment scattered loads serialized on the vmcnt drain.
// Reverted to LDS staging for both operands (v4 = 74us baseline).
// v4's residual: 1 block/CU -> all 8 waves barrier-aligned -> LDS-port phase
// (1536cyc) and MFMA phase (1240cyc) SERIALIZE (tile = 2775cyc = exact sum).
// v6 fix: 2 independent blocks per CU. Block tile 128x128, 256 threads
// (4 waves, 2x2 of 64x64), grid 32x16 = 512 blocks = 2/CU. Blocks share no
// barrier, so one block's MFMA phase overlaps the other's LDS/stage phase
// (m114: pipes co-schedule across waves). Per-CU tile-pair bound ~=
// max(port ~2300, MFMA 2480) vs v4's 2775 per single tile.
// LDS: 2 buffers x (A 16KB + B 16KB) = 64KB/block (fits 2 blocks/CU).
// Staging via global_load_lds (8 GLD/thread/tile), chunk-XOR swizzle
// (verified 0 bank conflicts). Distance-1 prefetch, vmcnt(0)+barrier once
// per tile - the drain is covered by the sibling block.
// MFMA per-acc order unchanged -> numerics bitwise identical.

#define GLD(gp, lp) __builtin_amdgcn_global_load_lds(                      \
        (const __attribute__((address_space(1))) void*)(gp),               \
        (__attribute__((address_space(3))) void*)(lp), 16, 0, 0)

#define MFMA(d, a, b) d = __builtin_amdgcn_mfma_f32_16x16x32_bf16(a, b, d, 0, 0, 0)

template <typename OutT, bool RELU>
__global__ __launch_bounds__(256, 2) void gemm_p8(const ushort_t* __restrict__ A,
                                                  const ushort_t* __restrict__ BT,
                                                  const float* __restrict__ bias,
                                                  OutT* __restrict__ C, int Kdim) {
    __shared__ __align__(16) ushort_t As[2][128 * 64];   // 32 KB
    __shared__ __align__(16) ushort_t Bs[2][128 * 64];   // 32 KB

    const int t = threadIdx.x;
    const int l = t & 63;
    const int w = t >> 6;          // wave 0..3
    const int l16 = l & 15;
    const int quad = l >> 4;
    const int wr = w >> 1;         // 0..1  (M)
    const int wc = w & 1;          // 0..1  (N)
    const int m0 = blockIdx.y * 128;
    const int n0 = blockIdx.x * 128;

    f32x4 acc[4][4];
#pragma unroll
    for (int i = 0; i < 4; ++i)
#pragma unroll
        for (int j = 0; j < 4; ++j) acc[i][j] = (f32x4){0.f, 0.f, 0.f, 0.f};

    // --- staging addressing (chunk-XOR swizzle, verified conflict-free) ---
    // 256 threads cover 32 rows x 8 chunks per round; 4 rounds each for A,B.
    // lane l of wave w -> row w*8 + (l>>3) + round*32, LDS chunk l&7 (linear
    // dest = base + l*16B); global source chunk inverse-swizzled.
    const int srow = t >> 3;                      // 0..31
    const int scol = ((t & 7) ^ (srow & 7)) * 8;  // swizzled 16B chunk
    const ushort_t* gA = A  + (size_t)(m0 + srow) * Kdim + scol;
    const ushort_t* gB = BT + (size_t)(n0 + srow) * Kdim + scol;
    const int ldsW = w * 8 * 64;   // wave-uniform element offset within a round

    // fragment reads: row = wtile + i*16 + l16, chunk slot = (kk*4+quad)^(row&7)
    const int swz = l16 & 7;       // == row&7 for all fragment rows
#define LDA_(base, i, kk) (*(const bf16x8*)&(base)[(wr * 64 + (i) * 16 + l16) * 64 + ((((kk) * 4 + quad) ^ swz) * 8)])
#define LDB_(base, j, kk) (*(const bf16x8*)&(base)[(wc * 64 + (j) * 16 + l16) * 64 + ((((kk) * 4 + quad) ^ swz) * 8)])

    const size_t rstep = (size_t)32 * Kdim;       // 32 rows of global stride
#define STAGE_TILE(buf, koff) do {                                  \
        GLD(gA + (koff),             &As[buf][ldsW]);               \
        GLD(gA + (koff) + rstep,     &As[buf][ldsW + 32 * 64]);     \
        GLD(gA + (koff) + 2 * rstep, &As[buf][ldsW + 64 * 64]);     \
        GLD(gA + (koff) + 3 * rstep, &As[buf][ldsW + 96 * 64]);     \
        GLD(gB + (koff),             &Bs[buf][ldsW]);               \
        GLD(gB + (koff) + rstep,     &Bs[buf][ldsW + 32 * 64]);     \
        GLD(gB + (koff) + 2 * rstep, &Bs[buf][ldsW + 64 * 64]);     \
        GLD(gB + (koff) + 3 * rstep, &Bs[buf][ldsW + 96 * 64]);     \
    } while (0)

    // 16 MFMAs at one kk (i-major, j-minor -> per-acc order identical to prior versions)
#define MFMA16(a0, a1, a2, a3, b0, b1, b2, b3)                     \
        MFMA(acc[0][0], a0, b0); MFMA(acc[0][1], a0, b1);          \
        MFMA(acc[0][2], a0, b2); MFMA(acc[0][3], a0, b3);          \
        MFMA(acc[1][0], a1, b0); MFMA(acc[1][1], a1, b1);          \
        MFMA(acc[1][2], a1, b2); MFMA(acc[1][3], a1, b3);          \
        MFMA(acc[2][0], a2, b0); MFMA(acc[2][1], a2, b1);          \
        MFMA(acc[2][2], a2, b2); MFMA(acc[2][3], a2, b3);          \
        MFMA(acc[3][0], a3, b0); MFMA(acc[3][1], a3, b1);          \
        MFMA(acc[3][2], a3, b2); MFMA(acc[3][3], a3, b3)

    const int nt = Kdim >> 6;      // K-tiles of 64

    // prologue: stage tile 0, drain, sync
    STAGE_TILE(0, 0);
    asm volatile("s_waitcnt vmcnt(0)" ::: "memory");
    __builtin_amdgcn_s_barrier();

    for (int tt = 0; tt < nt; ++tt) {
        const int buf = tt & 1;

        // stage tile tt+1 into the other buffer (its readers finished at the
        // barrier ending tile tt-1); issued first so HBM latency hides under
        // this tile's ds_reads + MFMAs.
        if (tt + 1 < nt) STAGE_TILE(buf ^ 1, (tt + 1) << 6);
        __builtin_amdgcn_sched_barrier(0);

        const ushort_t* __restrict__ Ab = &As[buf][0];
        const ushort_t* __restrict__ Bb = &Bs[buf][0];

        // all 16 fragment reads of this K-tile (counted lgkmcnt by compiler)
        bf16x8 a00 = LDA_(Ab, 0, 0), a01 = LDA_(Ab, 1, 0), a02 = LDA_(Ab, 2, 0), a03 = LDA_(Ab, 3, 0);
        bf16x8 b00 = LDB_(Bb, 0, 0), b01 = LDB_(Bb, 1, 0), b02 = LDB_(Bb, 2, 0), b03 = LDB_(Bb, 3, 0);
        bf16x8 a10 = LDA_(Ab, 0, 1), a11 = LDA_(Ab, 1, 1), a12 = LDA_(Ab, 2, 1), a13 = LDA_(Ab, 3, 1);
        bf16x8 b10 = LDB_(Bb, 0, 1), b11 = LDB_(Bb, 1, 1), b12 = LDB_(Bb, 2, 1), b13 = LDB_(Bb, 3, 1);

        // 32 MFMAs, single barrier-free region
        MFMA16(a00, a01, a02, a03, b00, b01, b02, b03);
        MFMA16(a10, a11, a12, a13, b10, b11, b12, b13);

        if (tt + 1 < nt) {
            // next iter reads buf^1: all waves' 8 GLDs must be done & visible
            asm volatile("s_waitcnt vmcnt(0)" ::: "memory");
            __builtin_amdgcn_s_barrier();
        }
    }

    // epilogue: C/D layout col=lane&15, row=quad*4+reg (unchanged mapping)
#pragma unroll
    for (int i = 0; i < 4; ++i) {
#pragma unroll
        for (int r = 0; r < 4; ++r) {
            const int grow = m0 + wr * 64 + i * 16 + quad * 4 + r;
#pragma unroll
            for (int j = 0; j < 4; ++j) {
                const int gcol = n0 + wc * 64 + j * 16 + l16;
                float v = acc[i][j][r] + bias[gcol];
                if (RELU) v = fmaxf(v, 0.0f);
                if constexpr (sizeof(OutT) == 2) {
                    C[(size_t)grow * NDIM + gcol] = to_bf16(v);
                } else {
                    C[(size_t)grow * NDIM + gcol] = v;
                }
            }
        }
    }
}

// ---------------- Sinkhorn, factored: P = diag(a) K diag(b) ----------------
// (unchanged — register-resident K, readlane broadcast)
__device__ __forceinline__ float rdl(float v, int l) {
    return __uint_as_float(__builtin_amdgcn_readlane(__float_as_uint(v), l));
}

__global__ __launch_bounds__(64) void sinkhorn_kernel(float* __restrict__ PM) {
    __shared__ __align__(16) float T[64 * 65];  // one-time transpose staging
    const int l = threadIdx.x;
    float* base = PM + (size_t)blockIdx.x * 4096;

    float Kcol[64];  // Kcol[r] = K[r][l]  (column l)
    float Krow[64];  // Krow[c] = K[l][c]  (row l)
#pragma unroll
    for (int r = 0; r < 64; ++r)
        Kcol[r] = __expf(-base[r * 64 + l]);
#pragma unroll
    for (int r = 0; r < 64; ++r)
        T[r * 65 + l] = Kcol[r];
    __syncthreads();
#pragma unroll
    for (int c = 0; c < 64; ++c)
        Krow[c] = T[l * 65 + c];

    float a = 0.0f, b = 1.0f;
    for (int it = 0; it < 1000; ++it) {
        float t1 = 0.0f;  // (K b)_row=l
#pragma unroll
        for (int c = 0; c < 64; ++c)
            t1 = fmaf(Krow[c], rdl(b, c), t1);
        a = 0.015625f / t1;  // r = 1/64

        float t2 = 0.0f;  // (K^T a)_col=l
#pragma unroll
        for (int r = 0; r < 64; ++r)
            t2 = fmaf(Kcol[r], rdl(a, r), t2);
        const float err = fabsf(b * t2 - 0.015625f);
        if (__ballot(err > 1e-6f) == 0ull) break;
        b = 0.015625f / t2;
    }

#pragma unroll
    for (int r = 0; r < 64; ++r)
        base[r * 64 + l] = rdl(a, r) * Kcol[r] * b;
}

extern "C" void kernel_launch(void* const* d_in, const int* in_sizes, int n_in,
                              void* d_out, int out_size, void* d_ws, size_t ws_size,
                              hipStream_t stream) {
    const float* z  = (const float*)d_in[0];
    const float* W1 = (const float*)d_in[1];
    const float* b1 = (const float*)d_in[2];
    const float* W2 = (const float*)d_in[3];
    const float* b2 = (const float*)d_in[4];
    const float* W3 = (const float*)d_in[5];
    const float* b3 = (const float*)d_in[6];
    float* out = (float*)d_out;
    char* ws = (char*)d_ws;

    // workspace layout (bytes)
    ushort_t* W2T = (ushort_t*)(ws + 0);                       // 4096*4096*2 = 32 MB
    ushort_t* W3T = (ushort_t*)(ws + (size_t)33554432);        // 32 MB
    ushort_t* C1b = (ushort_t*)(ws + (size_t)67108864);        // 2048*4096*2 = 16 MB
    ushort_t* C2b = (ushort_t*)(ws + (size_t)83886080);        // 16 MB
    ushort_t* Zb  = (ushort_t*)(ws + (size_t)100663296);       // 2048*256*2 = 1 MB
    ushort_t* W1T = (ushort_t*)(ws + (size_t)101711872);       // 4096*256*2 = 2 MB

    // prep
    cast_bf16_kernel<<<2048, 256, 0, stream>>>(z, Zb, MDIM * 256);
    transpose_cast_kernel<<<dim3(128, 8), dim3(32, 8), 0, stream>>>(W1, W1T, 256, 4096);
    transpose_cast_kernel<<<dim3(128, 128), dim3(32, 8), 0, stream>>>(W2, W2T, 4096, 4096);
    transpose_cast_kernel<<<dim3(128, 128), dim3(32, 8), 0, stream>>>(W3, W3T, 4096, 4096);

    // 3-layer MLP (bf16 MFMA, fp32 accum); layer 3 writes fp32 cost matrix into d_out
    gemm_p8<ushort_t, true><<<dim3(NDIM / 128, MDIM / 128), 256, 0, stream>>>(Zb, W1T, b1, C1b, 256);
    gemm_p8<ushort_t, true><<<dim3(NDIM / 128, MDIM / 128), 256, 0, stream>>>(C1b, W2T, b2, C2b, 4096);
    gemm_p8<float, false><<<dim3(NDIM / 128, MDIM / 128), 256, 0, stream>>>(C2b, W3T, b3, out, 4096);

    // Sinkhorn in-place on d_out (one wave per matrix, register-resident K)
    sinkhorn_kernel<<<2048, 64, 0, stream>>>(out);
}